// Round 3
// baseline (5002.431 us; speedup 1.0000x reference)
//
#include <hip/hip_runtime.h>
#include <math.h>

#define HW 320
#define IMGSZ (HW*HW)
#define NB 4

__device__ __forceinline__ float4 ld4(const float* p){ return *reinterpret_cast<const float4*>(p); }

// ---------------------------------------------------------------------------
// adconv metadata: indexs=argmax(para,1); perm=stable argsort(indexs);
// mul[t]=sum(para max | idx==t)/max(cnt,1)+1. Slot k: src=perm[k],
// d=indexs[src]+1, scale=mul[indexs[src]].
// ---------------------------------------------------------------------------
__global__ void meta_kernel(const float* p0,const float* p1,const float* p2,
                            const float* p3,const float* p4,const float* p5,
                            int* msrc,int* md,float* mscale){
  if (threadIdx.x != 0) return;
  int set = blockIdx.x;
  const float* ps[6] = {p0,p1,p2,p3,p4,p5};
  const int Ts[6] = {1,3,1,3,1,3};   // c1f, c2f, c1b, c2b, c1g, c2g
  const float* para = ps[set];
  int T = Ts[set];
  int idx[32]; float mx[32];
  for (int c=0;c<32;c++){
    int best=0; float bv=para[c*T];
    for (int t=1;t<T;t++){ float v=para[c*T+t]; if (v>bv){bv=v;best=t;} }
    idx[c]=best; mx[c]=bv;
  }
  float sum[3]={0.f,0.f,0.f}; int cnt[3]={0,0,0};
  for (int c=0;c<32;c++){ sum[idx[c]] += mx[c]; cnt[idx[c]]++; }
  float mul[3];
  for (int t=0;t<3;t++) mul[t] = sum[t]/fmaxf((float)cnt[t],1.f)+1.f;
  int off[3]; off[0]=0; off[1]=cnt[0]; off[2]=cnt[0]+cnt[1];
  int perm[32];
  for (int c=0;c<32;c++) perm[off[idx[c]]++] = c;   // stable counting sort
  for (int k=0;k<32;k++){
    int s = perm[k];
    msrc[set*32+k]=s; md[set*32+k]=idx[s]+1; mscale[set*32+k]=mul[idx[s]];
  }
}

// u = x + xi*(x - xprev)
__global__ void ew_u(const float* __restrict__ x, const float* __restrict__ xprev,
                     const float* __restrict__ t_p, float* __restrict__ u, int n4){
  int i = blockIdx.x*blockDim.x + threadIdx.x;
  if (i >= n4) return;
  float t = *t_p;
  float tplus = (1.f + sqrtf(1.f + 4.f*t*t)) * 0.5f;
  float xi = (t - 1.f)/tplus;
  float4 xv = ld4(x + 4*i); float4 pv = ld4(xprev + 4*i);
  float4 r;
  r.x = xv.x + xi*(xv.x-pv.x);
  r.y = xv.y + xi*(xv.y-pv.y);
  r.z = xv.z + xi*(xv.z-pv.z);
  r.w = xv.w + xi*(xv.w-pv.w);
  *reinterpret_cast<float4*>(u + 4*i) = r;
}

// phi[b,c,blk,m] (per-channel!)   grid(100,3,4) x 256
__global__ void phi_fwd(const float* __restrict__ u, const float* __restrict__ PhiW,
                        float* __restrict__ phi){
  int blk = blockIdx.x, c = blockIdx.y, b = blockIdx.z;
  int bh = blk/10, bw = blk%10;
  __shared__ float ub[1024];
  int tid = threadIdx.x;
  {
    int i = tid >> 3, j4 = (tid & 7) << 2;
    const float* src = u + (size_t)((b*3 + c)*HW + bh*32 + i)*HW + bw*32 + j4;
    *reinterpret_cast<float4*>(ub + i*32 + j4) = ld4(src);
  }
  __syncthreads();
  int m = tid;
  const float* wp = PhiW + (size_t)(m*3 + c)*1024;
  float acc = 0.f;
  #pragma unroll 8
  for (int q = 0; q < 1024; q += 4){
    float4 w = ld4(wp + q);
    float4 uv = *reinterpret_cast<const float4*>(ub + q);
    acc += w.x*uv.x + w.y*uv.y + w.z*uv.z + w.w*uv.w;
  }
  phi[((size_t)(b*3 + c)*100 + blk)*256 + m] = acc;
}

// x_input = u - lam*phitphi + lam*PhiTb   grid(100,3,4) x 256
__global__ void phit_zeta(const float* __restrict__ phi, const float* __restrict__ PhiTW,
                          const float* __restrict__ u, const float* __restrict__ PhiTb,
                          const float* __restrict__ lam_p, float* __restrict__ x_input){
  int blk = blockIdx.x, c = blockIdx.y, b = blockIdx.z;
  int bh = blk/10, bw = blk%10;
  __shared__ float pb[256];
  int tid = threadIdx.x;
  pb[tid] = phi[((size_t)(b*3 + c)*100 + blk)*256 + tid];
  __syncthreads();
  float lam = *lam_p;
  for (int nn = tid; nn < 1024; nn += 256){
    const float* wp = PhiTW + (size_t)(c*1024 + nn)*256;
    float acc = 0.f;
    #pragma unroll 8
    for (int q=0;q<256;q+=4){
      float4 w = ld4(wp+q);
      float4 pv = *reinterpret_cast<const float4*>(pb+q);
      acc += w.x*pv.x + w.y*pv.y + w.z*pv.z + w.w*pv.w;
    }
    int i = nn>>5, j = nn&31;
    size_t g = (size_t)((b*3+c)*HW + bh*32+i)*HW + bw*32 + j;
    x_input[g] = u[g] - lam*acc + lam*PhiTb[g];
  }
}

// ---------------------------------------------------------------------------
// 3x3 conv, "same", dilation D (template). Each block: 64x64 px tile, NK
// output-channel slots (amortizes input reads NK-fold). Grid (COUT/NK, 25, NB)
// with channel-group fastest so same-tile blocks are dispatch-adjacent.
// msrc/md/mscale per-slot (nullptr => identity). ITRANS: 0 none,1 relu,
// 2 soft-thr. EPI: 0 none,1 relu,2 merge(epi+ms*v),3 sub(v-epi).
// ---------------------------------------------------------------------------
template<int CIN, int COUT, int NK, int D, int ITRANS, int EPI>
__global__ __launch_bounds__(256)
void conv3x3(const float* __restrict__ in, const float* __restrict__ wts,
             float* __restrict__ out,
             const int* __restrict__ msrc, const int* __restrict__ md,
             const float* __restrict__ mscale,
             const float* __restrict__ thr_p,
             const float* __restrict__ epi_ptr,
             const float* __restrict__ ms_p){
  const int kg = blockIdx.x;
  const int b  = blockIdx.z;
  const int k0 = kg*NK;
  const int tile = blockIdx.y;

  bool act[NK]; float scl[NK]; bool any = false;
  #pragma unroll
  for (int kk=0;kk<NK;kk++){
    int k = k0+kk;
    int d = md ? md[k] : 1;
    act[kk] = (d==D);
    scl[kk] = mscale ? mscale[k] : 1.f;
    any = any || act[kk];
  }
  if (!any) return;   // wave-uniform

  __shared__ float wsm[NK*CIN*12];   // 9 taps padded to 12 for float4 reads
  int tid = threadIdx.y*16 + threadIdx.x;
  for (int q = tid; q < NK*CIN*9; q += 256){
    int kk = q/(CIN*9); int rem = q - kk*(CIN*9); int ic = rem/9; int t = rem - ic*9;
    int src = msrc ? msrc[k0+kk] : (k0+kk);
    wsm[(kk*CIN+ic)*12 + t] = wts[(size_t)src*(CIN*9) + rem];
  }
  __syncthreads();

  const int x0 = (tile%5)*64 + threadIdx.x*4;
  const int y0 = (tile/5)*64 + threadIdx.y*4;
  const float thr = (ITRANS==2) ? *thr_p : 0.f;
  float acc[NK][4][4] = {};

  for (int ic=0; ic<CIN; ++ic){
    const float* ip = in + (size_t)(b*CIN+ic)*IMGSZ;
    float wk[NK][9];
    #pragma unroll
    for (int kk=0;kk<NK;kk++){
      if (act[kk]){
        const float* wp = &wsm[(kk*CIN+ic)*12];
        float4 a = *reinterpret_cast<const float4*>(wp);
        float4 bb= *reinterpret_cast<const float4*>(wp+4);
        float4 cc= *reinterpret_cast<const float4*>(wp+8);
        wk[kk][0]=a.x; wk[kk][1]=a.y; wk[kk][2]=a.z; wk[kk][3]=a.w;
        wk[kk][4]=bb.x; wk[kk][5]=bb.y; wk[kk][6]=bb.z; wk[kk][7]=bb.w;
        wk[kk][8]=cc.x;
      }
    }
    #pragma unroll
    for (int r=0; r<4+2*D; ++r){
      int yr = y0 - D + r;
      if (yr < 0 || yr >= HW) continue;
      const float* rp = ip + (size_t)yr*HW;
      float4 v0 = (x0 >= 4)    ? ld4(rp + x0-4) : float4{0.f,0.f,0.f,0.f};
      float4 v1 = ld4(rp + x0);
      float4 v2 = (x0+4 < HW)  ? ld4(rp + x0+4) : float4{0.f,0.f,0.f,0.f};
      float w12[12] = {v0.x,v0.y,v0.z,v0.w, v1.x,v1.y,v1.z,v1.w, v2.x,v2.y,v2.z,v2.w};
      if (ITRANS==1){
        #pragma unroll
        for (int q=0;q<12;q++) w12[q] = fmaxf(w12[q],0.f);
      } else if (ITRANS==2){
        #pragma unroll
        for (int q=0;q<12;q++){
          float a = fabsf(w12[q]) - thr;
          w12[q] = (a > 0.f) ? copysignf(a, w12[q]) : 0.f;
        }
      }
      #pragma unroll
      for (int kk=0;kk<NK;kk++){
        if (!act[kk]) continue;   // wave-uniform skip
        #pragma unroll
        for (int ky=0; ky<3; ++ky){
          int j = r - ky*D;
          if (j >= 0 && j < 4){
            #pragma unroll
            for (int p=0;p<4;p++){
              #pragma unroll
              for (int kx=0;kx<3;kx++)
                acc[kk][j][p] += wk[kk][ky*3+kx] * w12[4 + p + (kx-1)*D];
            }
          }
        }
      }
    }
  }

  float ms = (EPI==2) ? *ms_p : 0.f;
  #pragma unroll
  for (int kk=0;kk<NK;kk++){
    if (!act[kk]) continue;
    int k = k0+kk;
    #pragma unroll
    for (int j=0;j<4;j++){
      size_t oidx = ((size_t)(b*COUT + k)*HW + (y0+j))*HW + x0;
      float4 o;
      float* op = reinterpret_cast<float*>(&o);
      #pragma unroll
      for (int p=0;p<4;p++){
        float v = acc[kk][j][p]*scl[kk];
        if (EPI==1) v = fmaxf(v,0.f);
        else if (EPI==2) v = epi_ptr[oidx+p] + ms*v;
        else if (EPI==3) v = v - epi_ptr[oidx+p];
        op[p] = v;
      }
      *reinterpret_cast<float4*>(out + oidx) = o;
    }
  }
}

// ---------------------------------------------------------------------------
extern "C" void kernel_launch(void* const* d_in, const int* in_sizes, int n_in,
                              void* d_out, int out_size, void* d_ws, size_t ws_size,
                              hipStream_t stream) {
  const float* xprev = (const float*)d_in[0];
  const float* x     = (const float*)d_in[1];
  const float* PhiW  = (const float*)d_in[2];
  const float* PhiTW = (const float*)d_in[3];
  const float* PhiTb = (const float*)d_in[4];
  const float* lam   = (const float*)d_in[5];
  const float* sthr  = (const float*)d_in[6];
  const float* t_p   = (const float*)d_in[7];
  const float* mrg   = (const float*)d_in[8];
  const float* convD = (const float*)d_in[9];
  const float* conv3G= (const float*)d_in[10];
  const float* c1f_w=(const float*)d_in[11]; const float* c1f_p=(const float*)d_in[12];
  const float* c2f_w=(const float*)d_in[13]; const float* c2f_p=(const float*)d_in[14];
  const float* c1b_w=(const float*)d_in[15]; const float* c1b_p=(const float*)d_in[16];
  const float* c2b_w=(const float*)d_in[17]; const float* c2b_p=(const float*)d_in[18];
  const float* c1g_w=(const float*)d_in[19]; const float* c1g_p=(const float*)d_in[20];
  const float* c2g_w=(const float*)d_in[21]; const float* c2g_p=(const float*)d_in[22];

  char* ws = (char*)d_ws;
  const size_t BIG = (size_t)NB*32*IMGSZ*sizeof(float);     // 52,428,800
  float* A       = (float*)(ws);                // x_D (kept for symloss)
  float* Bb      = (float*)(ws + BIG);
  float* Cc      = (float*)(ws + 2*BIG);        // x_forward (kept)
  float* Dd      = (float*)(ws + 3*BIG);
  float* x_input = (float*)(ws + 4*BIG);                      // 4.9 MB
  float* u       = (float*)(ws + 4*BIG + 4915200);            // 4.9 MB
  float* phi     = (float*)(ws + 4*BIG + 2*4915200);          // 4.9 MB (per-channel)
  char*  mbase   = ws + 4*BIG + 3*4915200;
  int*   msrc    = (int*)(mbase);
  int*   md      = (int*)(mbase + 6*32*4);
  float* mscale  = (float*)(mbase + 2*6*32*4);

  float* out0 = (float*)d_out;
  float* out1 = out0 + (size_t)NB*3*IMGSZ;

  dim3 cb(16,16);
  dim3 g32(8,25,NB);    // 32 out channels / NK=4
  dim3 g3(3,25,NB);     // 3 out channels, NK=1

  // meta sets: 0=c1f 1=c2f 2=c1b 3=c2b 4=c1g 5=c2g
  meta_kernel<<<6, 64, 0, stream>>>(c1f_p,c2f_p,c1b_p,c2b_p,c1g_p,c2g_p, msrc,md,mscale);

  ew_u<<<1200, 256, 0, stream>>>(x, xprev, t_p, u, 307200);
  phi_fwd<<<dim3(100,3,NB), 256, 0, stream>>>(u, PhiW, phi);
  phit_zeta<<<dim3(100,3,NB), 256, 0, stream>>>(phi, PhiTW, u, PhiTb, lam, x_input);

  // x_D = conv_D(x_input)
  conv3x3<3,32,4,1,0,0><<<g32,cb,0,stream>>>(x_input, convD, A, nullptr,nullptr,nullptr, nullptr,nullptr,nullptr);
  // h1 = relu(adconv(x_D, c1f))
  conv3x3<32,32,4,1,0,1><<<g32,cb,0,stream>>>(A, c1f_w, Bb, msrc, md, mscale, nullptr,nullptr,nullptr);
  // x_forward = adconv(h1, c2f)
  conv3x3<32,32,4,1,0,0><<<g32,cb,0,stream>>>(Bb, c2f_w, Cc, msrc+32, md+32, mscale+32, nullptr,nullptr,nullptr);
  conv3x3<32,32,4,2,0,0><<<g32,cb,0,stream>>>(Bb, c2f_w, Cc, msrc+32, md+32, mscale+32, nullptr,nullptr,nullptr);
  conv3x3<32,32,4,3,0,0><<<g32,cb,0,stream>>>(Bb, c2f_w, Cc, msrc+32, md+32, mscale+32, nullptr,nullptr,nullptr);
  // h2 = relu(adconv(soft(x_forward), c1f))
  conv3x3<32,32,4,1,2,1><<<g32,cb,0,stream>>>(Cc, c1f_w, Dd, msrc, md, mscale, sthr,nullptr,nullptr);
  // x_backward = adconv(h2, c2b)
  conv3x3<32,32,4,1,0,0><<<g32,cb,0,stream>>>(Dd, c2b_w, Bb, msrc+96, md+96, mscale+96, nullptr,nullptr,nullptr);
  conv3x3<32,32,4,2,0,0><<<g32,cb,0,stream>>>(Dd, c2b_w, Bb, msrc+96, md+96, mscale+96, nullptr,nullptr,nullptr);
  conv3x3<32,32,4,3,0,0><<<g32,cb,0,stream>>>(Dd, c2b_w, Bb, msrc+96, md+96, mscale+96, nullptr,nullptr,nullptr);
  // h3 = adconv(relu(x_backward), c1g)
  conv3x3<32,32,4,1,1,0><<<g32,cb,0,stream>>>(Bb, c1g_w, Dd, msrc+128, md+128, mscale+128, nullptr,nullptr,nullptr);
  // h4 = adconv(relu(h3), c2g)
  conv3x3<32,32,4,1,1,0><<<g32,cb,0,stream>>>(Dd, c2g_w, Bb, msrc+160, md+160, mscale+160, nullptr,nullptr,nullptr);
  conv3x3<32,32,4,2,1,0><<<g32,cb,0,stream>>>(Dd, c2g_w, Bb, msrc+160, md+160, mscale+160, nullptr,nullptr,nullptr);
  conv3x3<32,32,4,3,1,0><<<g32,cb,0,stream>>>(Dd, c2g_w, Bb, msrc+160, md+160, mscale+160, nullptr,nullptr,nullptr);
  // x_pred = x_input + mergeScale * conv3_G(h4)  -> out0
  conv3x3<32,3,1,1,0,2><<<g3,cb,0,stream>>>(Bb, conv3G, out0, nullptr,nullptr,nullptr, nullptr, x_input, mrg);
  // h5 = relu(adconv(x_forward, c1b))
  conv3x3<32,32,4,1,0,1><<<g32,cb,0,stream>>>(Cc, c1b_w, Dd, msrc+64, md+64, mscale+64, nullptr,nullptr,nullptr);
  // symloss = adconv(h5, c2b) - x_D  -> out1
  conv3x3<32,32,4,1,0,3><<<g32,cb,0,stream>>>(Dd, c2b_w, out1, msrc+96, md+96, mscale+96, nullptr, A, nullptr);
  conv3x3<32,32,4,2,0,3><<<g32,cb,0,stream>>>(Dd, c2b_w, out1, msrc+96, md+96, mscale+96, nullptr, A, nullptr);
  conv3x3<32,32,4,3,0,3><<<g32,cb,0,stream>>>(Dd, c2b_w, out1, msrc+96, md+96, mscale+96, nullptr, A, nullptr);
}

// Round 4
// 4717.187 us; speedup vs baseline: 1.0605x; 1.0605x over previous
//
#include <hip/hip_runtime.h>
#include <math.h>

#define HW 320
#define IMGSZ (HW*HW)
#define NB 4

__device__ __forceinline__ float4 ld4(const float* p){ return *reinterpret_cast<const float4*>(p); }

// ---------------------------------------------------------------------------
// adconv metadata: indexs=argmax(para,1); perm=stable argsort(indexs);
// mul[t]=sum(para max | idx==t)/max(cnt,1)+1. Slot k: src=perm[k],
// d=indexs[src]+1, scale=mul[indexs[src]].
// ---------------------------------------------------------------------------
__global__ void meta_kernel(const float* p0,const float* p1,const float* p2,
                            const float* p3,const float* p4,const float* p5,
                            int* msrc,int* md,float* mscale){
  if (threadIdx.x != 0) return;
  int set = blockIdx.x;
  const float* ps[6] = {p0,p1,p2,p3,p4,p5};
  const int Ts[6] = {1,3,1,3,1,3};   // c1f, c2f, c1b, c2b, c1g, c2g
  const float* para = ps[set];
  int T = Ts[set];
  int idx[32]; float mx[32];
  for (int c=0;c<32;c++){
    int best=0; float bv=para[c*T];
    for (int t=1;t<T;t++){ float v=para[c*T+t]; if (v>bv){bv=v;best=t;} }
    idx[c]=best; mx[c]=bv;
  }
  float sum[3]={0.f,0.f,0.f}; int cnt[3]={0,0,0};
  for (int c=0;c<32;c++){ sum[idx[c]] += mx[c]; cnt[idx[c]]++; }
  float mul[3];
  for (int t=0;t<3;t++) mul[t] = sum[t]/fmaxf((float)cnt[t],1.f)+1.f;
  int off[3]; off[0]=0; off[1]=cnt[0]; off[2]=cnt[0]+cnt[1];
  int perm[32];
  for (int c=0;c<32;c++) perm[off[idx[c]]++] = c;   // stable counting sort
  for (int k=0;k<32;k++){
    int s = perm[k];
    msrc[set*32+k]=s; md[set*32+k]=idx[s]+1; mscale[set*32+k]=mul[idx[s]];
  }
}

// u = x + xi*(x - xprev)
__global__ void ew_u(const float* __restrict__ x, const float* __restrict__ xprev,
                     const float* __restrict__ t_p, float* __restrict__ u, int n4){
  int i = blockIdx.x*blockDim.x + threadIdx.x;
  if (i >= n4) return;
  float t = *t_p;
  float tplus = (1.f + sqrtf(1.f + 4.f*t*t)) * 0.5f;
  float xi = (t - 1.f)/tplus;
  float4 xv = ld4(x + 4*i); float4 pv = ld4(xprev + 4*i);
  float4 r;
  r.x = xv.x + xi*(xv.x-pv.x);
  r.y = xv.y + xi*(xv.y-pv.y);
  r.z = xv.z + xi*(xv.z-pv.z);
  r.w = xv.w + xi*(xv.w-pv.w);
  *reinterpret_cast<float4*>(u + 4*i) = r;
}

// phi[b,c,blk,m] (per-channel!)   grid(100,3,4) x 256
__global__ void phi_fwd(const float* __restrict__ u, const float* __restrict__ PhiW,
                        float* __restrict__ phi){
  int blk = blockIdx.x, c = blockIdx.y, b = blockIdx.z;
  int bh = blk/10, bw = blk%10;
  __shared__ float ub[1024];
  int tid = threadIdx.x;
  {
    int i = tid >> 3, j4 = (tid & 7) << 2;
    const float* src = u + (size_t)((b*3 + c)*HW + bh*32 + i)*HW + bw*32 + j4;
    *reinterpret_cast<float4*>(ub + i*32 + j4) = ld4(src);
  }
  __syncthreads();
  int m = tid;
  const float* wp = PhiW + (size_t)(m*3 + c)*1024;
  float acc = 0.f;
  #pragma unroll 8
  for (int q = 0; q < 1024; q += 4){
    float4 w = ld4(wp + q);
    float4 uv = *reinterpret_cast<const float4*>(ub + q);
    acc += w.x*uv.x + w.y*uv.y + w.z*uv.z + w.w*uv.w;
  }
  phi[((size_t)(b*3 + c)*100 + blk)*256 + m] = acc;
}

// x_input = u - lam*phitphi + lam*PhiTb   grid(100,3,4) x 256
__global__ void phit_zeta(const float* __restrict__ phi, const float* __restrict__ PhiTW,
                          const float* __restrict__ u, const float* __restrict__ PhiTb,
                          const float* __restrict__ lam_p, float* __restrict__ x_input){
  int blk = blockIdx.x, c = blockIdx.y, b = blockIdx.z;
  int bh = blk/10, bw = blk%10;
  __shared__ float pb[256];
  int tid = threadIdx.x;
  pb[tid] = phi[((size_t)(b*3 + c)*100 + blk)*256 + tid];
  __syncthreads();
  float lam = *lam_p;
  for (int nn = tid; nn < 1024; nn += 256){
    const float* wp = PhiTW + (size_t)(c*1024 + nn)*256;
    float acc = 0.f;
    #pragma unroll 8
    for (int q=0;q<256;q+=4){
      float4 w = ld4(wp+q);
      float4 pv = *reinterpret_cast<const float4*>(pb+q);
      acc += w.x*pv.x + w.y*pv.y + w.z*pv.z + w.w*pv.w;
    }
    int i = nn>>5, j = nn&31;
    size_t g = (size_t)((b*3+c)*HW + bh*32+i)*HW + bw*32 + j;
    x_input[g] = u[g] - lam*acc + lam*PhiTb[g];
  }
}

// ---------------------------------------------------------------------------
// 3x3 conv, "same", dilation D (template). Each block: 64x64 px tile, NK
// output-channel slots. BRANCH-FREE inner loop: inactive slots get zeroed
// weights in LDS (FMA work unconditional; only stores are predicated).
// __launch_bounds__(256,2): VGPR budget 256 so acc[NK][4][4]+weights stay
// in registers (round-3 regression: default alloc=76 VGPR spilled the accs,
// VALUBusy 8%).
// ITRANS: 0 none,1 relu,2 soft-thr. EPI: 0 none,1 relu,2 merge,3 sub.
// ---------------------------------------------------------------------------
template<int CIN, int COUT, int NK, int D, int ITRANS, int EPI>
__global__ __launch_bounds__(256, 2)
void conv3x3(const float* __restrict__ in, const float* __restrict__ wts,
             float* __restrict__ out,
             const int* __restrict__ msrc, const int* __restrict__ md,
             const float* __restrict__ mscale,
             const float* __restrict__ thr_p,
             const float* __restrict__ epi_ptr,
             const float* __restrict__ ms_p){
  const int kg = blockIdx.x;
  const int b  = blockIdx.z;
  const int k0 = kg*NK;
  const int tile = blockIdx.y;

  bool act[NK]; float scl[NK]; bool any = false;
  #pragma unroll
  for (int kk=0;kk<NK;kk++){
    int k = k0+kk;
    int d = md ? md[k] : 1;
    act[kk] = (d==D);
    scl[kk] = mscale ? mscale[k] : 1.f;
    any = any || act[kk];
  }
  if (!any) return;   // wave-uniform

  __shared__ float wsm[NK*CIN*12];   // 9 taps padded to 12 for float4 reads
  int tid = threadIdx.y*16 + threadIdx.x;
  for (int q = tid; q < NK*CIN*9; q += 256){
    int kk = q/(CIN*9); int rem = q - kk*(CIN*9); int ic = rem/9; int t = rem - ic*9;
    int src = msrc ? msrc[k0+kk] : (k0+kk);
    // inactive slot -> zero weights (keeps FMA core branch-free)
    wsm[(kk*CIN+ic)*12 + t] = act[kk] ? wts[(size_t)src*(CIN*9) + rem] : 0.f;
  }
  __syncthreads();

  const int x0 = (tile%5)*64 + threadIdx.x*4;
  const int y0 = (tile/5)*64 + threadIdx.y*4;
  const float thr = (ITRANS==2) ? *thr_p : 0.f;
  float acc[NK][4][4] = {};

  for (int ic=0; ic<CIN; ++ic){
    const float* ip = in + (size_t)(b*CIN+ic)*IMGSZ;
    float wk[NK][9];
    #pragma unroll
    for (int kk=0;kk<NK;kk++){
      const float* wp = &wsm[(kk*CIN+ic)*12];
      float4 a = *reinterpret_cast<const float4*>(wp);
      float4 bb= *reinterpret_cast<const float4*>(wp+4);
      float4 cc= *reinterpret_cast<const float4*>(wp+8);
      wk[kk][0]=a.x; wk[kk][1]=a.y; wk[kk][2]=a.z; wk[kk][3]=a.w;
      wk[kk][4]=bb.x; wk[kk][5]=bb.y; wk[kk][6]=bb.z; wk[kk][7]=bb.w;
      wk[kk][8]=cc.x;
    }
    #pragma unroll
    for (int r=0; r<4+2*D; ++r){
      int yr = y0 - D + r;
      if (yr < 0 || yr >= HW) continue;
      const float* rp = ip + (size_t)yr*HW;
      float4 v0 = (x0 >= 4)    ? ld4(rp + x0-4) : float4{0.f,0.f,0.f,0.f};
      float4 v1 = ld4(rp + x0);
      float4 v2 = (x0+4 < HW)  ? ld4(rp + x0+4) : float4{0.f,0.f,0.f,0.f};
      float w12[12] = {v0.x,v0.y,v0.z,v0.w, v1.x,v1.y,v1.z,v1.w, v2.x,v2.y,v2.z,v2.w};
      if (ITRANS==1){
        #pragma unroll
        for (int q=0;q<12;q++) w12[q] = fmaxf(w12[q],0.f);
      } else if (ITRANS==2){
        #pragma unroll
        for (int q=0;q<12;q++){
          float a = fabsf(w12[q]) - thr;
          w12[q] = (a > 0.f) ? copysignf(a, w12[q]) : 0.f;
        }
      }
      #pragma unroll
      for (int kk=0;kk<NK;kk++){
        #pragma unroll
        for (int ky=0; ky<3; ++ky){
          int j = r - ky*D;
          if (j >= 0 && j < 4){
            #pragma unroll
            for (int p=0;p<4;p++){
              #pragma unroll
              for (int kx=0;kx<3;kx++)
                acc[kk][j][p] += wk[kk][ky*3+kx] * w12[4 + p + (kx-1)*D];
            }
          }
        }
      }
    }
  }

  float ms = (EPI==2) ? *ms_p : 0.f;
  #pragma unroll
  for (int kk=0;kk<NK;kk++){
    if (!act[kk]) continue;   // store only live slots
    int k = k0+kk;
    #pragma unroll
    for (int j=0;j<4;j++){
      size_t oidx = ((size_t)(b*COUT + k)*HW + (y0+j))*HW + x0;
      float4 o;
      float* op = reinterpret_cast<float*>(&o);
      float4 e;
      if (EPI==2 || EPI==3) e = ld4(epi_ptr + oidx);
      #pragma unroll
      for (int p=0;p<4;p++){
        float v = acc[kk][j][p]*scl[kk];
        if (EPI==1) v = fmaxf(v,0.f);
        else if (EPI==2) v = reinterpret_cast<float*>(&e)[p] + ms*v;
        else if (EPI==3) v = v - reinterpret_cast<float*>(&e)[p];
        op[p] = v;
      }
      *reinterpret_cast<float4*>(out + oidx) = o;
    }
  }
}

// ---------------------------------------------------------------------------
extern "C" void kernel_launch(void* const* d_in, const int* in_sizes, int n_in,
                              void* d_out, int out_size, void* d_ws, size_t ws_size,
                              hipStream_t stream) {
  const float* xprev = (const float*)d_in[0];
  const float* x     = (const float*)d_in[1];
  const float* PhiW  = (const float*)d_in[2];
  const float* PhiTW = (const float*)d_in[3];
  const float* PhiTb = (const float*)d_in[4];
  const float* lam   = (const float*)d_in[5];
  const float* sthr  = (const float*)d_in[6];
  const float* t_p   = (const float*)d_in[7];
  const float* mrg   = (const float*)d_in[8];
  const float* convD = (const float*)d_in[9];
  const float* conv3G= (const float*)d_in[10];
  const float* c1f_w=(const float*)d_in[11]; const float* c1f_p=(const float*)d_in[12];
  const float* c2f_w=(const float*)d_in[13]; const float* c2f_p=(const float*)d_in[14];
  const float* c1b_w=(const float*)d_in[15]; const float* c1b_p=(const float*)d_in[16];
  const float* c2b_w=(const float*)d_in[17]; const float* c2b_p=(const float*)d_in[18];
  const float* c1g_w=(const float*)d_in[19]; const float* c1g_p=(const float*)d_in[20];
  const float* c2g_w=(const float*)d_in[21]; const float* c2g_p=(const float*)d_in[22];

  char* ws = (char*)d_ws;
  const size_t BIG = (size_t)NB*32*IMGSZ*sizeof(float);     // 52,428,800
  float* A       = (float*)(ws);                // x_D (kept for symloss)
  float* Bb      = (float*)(ws + BIG);
  float* Cc      = (float*)(ws + 2*BIG);        // x_forward (kept)
  float* Dd      = (float*)(ws + 3*BIG);
  float* x_input = (float*)(ws + 4*BIG);                      // 4.9 MB
  float* u       = (float*)(ws + 4*BIG + 4915200);            // 4.9 MB
  float* phi     = (float*)(ws + 4*BIG + 2*4915200);          // 4.9 MB (per-channel)
  char*  mbase   = ws + 4*BIG + 3*4915200;
  int*   msrc    = (int*)(mbase);
  int*   md      = (int*)(mbase + 6*32*4);
  float* mscale  = (float*)(mbase + 2*6*32*4);

  float* out0 = (float*)d_out;
  float* out1 = out0 + (size_t)NB*3*IMGSZ;

  dim3 cb(16,16);
  dim3 g32(8,25,NB);    // 32 out channels / NK=4
  dim3 g3(3,25,NB);     // 3 out channels, NK=1

  // meta sets: 0=c1f 1=c2f 2=c1b 3=c2b 4=c1g 5=c2g
  meta_kernel<<<6, 64, 0, stream>>>(c1f_p,c2f_p,c1b_p,c2b_p,c1g_p,c2g_p, msrc,md,mscale);

  ew_u<<<1200, 256, 0, stream>>>(x, xprev, t_p, u, 307200);
  phi_fwd<<<dim3(100,3,NB), 256, 0, stream>>>(u, PhiW, phi);
  phit_zeta<<<dim3(100,3,NB), 256, 0, stream>>>(phi, PhiTW, u, PhiTb, lam, x_input);

  // x_D = conv_D(x_input)
  conv3x3<3,32,4,1,0,0><<<g32,cb,0,stream>>>(x_input, convD, A, nullptr,nullptr,nullptr, nullptr,nullptr,nullptr);
  // h1 = relu(adconv(x_D, c1f))
  conv3x3<32,32,4,1,0,1><<<g32,cb,0,stream>>>(A, c1f_w, Bb, msrc, md, mscale, nullptr,nullptr,nullptr);
  // x_forward = adconv(h1, c2f)
  conv3x3<32,32,4,1,0,0><<<g32,cb,0,stream>>>(Bb, c2f_w, Cc, msrc+32, md+32, mscale+32, nullptr,nullptr,nullptr);
  conv3x3<32,32,4,2,0,0><<<g32,cb,0,stream>>>(Bb, c2f_w, Cc, msrc+32, md+32, mscale+32, nullptr,nullptr,nullptr);
  conv3x3<32,32,4,3,0,0><<<g32,cb,0,stream>>>(Bb, c2f_w, Cc, msrc+32, md+32, mscale+32, nullptr,nullptr,nullptr);
  // h2 = relu(adconv(soft(x_forward), c1f))
  conv3x3<32,32,4,1,2,1><<<g32,cb,0,stream>>>(Cc, c1f_w, Dd, msrc, md, mscale, sthr,nullptr,nullptr);
  // x_backward = adconv(h2, c2b)
  conv3x3<32,32,4,1,0,0><<<g32,cb,0,stream>>>(Dd, c2b_w, Bb, msrc+96, md+96, mscale+96, nullptr,nullptr,nullptr);
  conv3x3<32,32,4,2,0,0><<<g32,cb,0,stream>>>(Dd, c2b_w, Bb, msrc+96, md+96, mscale+96, nullptr,nullptr,nullptr);
  conv3x3<32,32,4,3,0,0><<<g32,cb,0,stream>>>(Dd, c2b_w, Bb, msrc+96, md+96, mscale+96, nullptr,nullptr,nullptr);
  // h3 = adconv(relu(x_backward), c1g)
  conv3x3<32,32,4,1,1,0><<<g32,cb,0,stream>>>(Bb, c1g_w, Dd, msrc+128, md+128, mscale+128, nullptr,nullptr,nullptr);
  // h4 = adconv(relu(h3), c2g)
  conv3x3<32,32,4,1,1,0><<<g32,cb,0,stream>>>(Dd, c2g_w, Bb, msrc+160, md+160, mscale+160, nullptr,nullptr,nullptr);
  conv3x3<32,32,4,2,1,0><<<g32,cb,0,stream>>>(Dd, c2g_w, Bb, msrc+160, md+160, mscale+160, nullptr,nullptr,nullptr);
  conv3x3<32,32,4,3,1,0><<<g32,cb,0,stream>>>(Dd, c2g_w, Bb, msrc+160, md+160, mscale+160, nullptr,nullptr,nullptr);
  // x_pred = x_input + mergeScale * conv3_G(h4)  -> out0
  conv3x3<32,3,1,1,0,2><<<g3,cb,0,stream>>>(Bb, conv3G, out0, nullptr,nullptr,nullptr, nullptr, x_input, mrg);
  // h5 = relu(adconv(x_forward, c1b))
  conv3x3<32,32,4,1,0,1><<<g32,cb,0,stream>>>(Cc, c1b_w, Dd, msrc+64, md+64, mscale+64, nullptr,nullptr,nullptr);
  // symloss = adconv(h5, c2b) - x_D  -> out1
  conv3x3<32,32,4,1,0,3><<<g32,cb,0,stream>>>(Dd, c2b_w, out1, msrc+96, md+96, mscale+96, nullptr, A, nullptr);
  conv3x3<32,32,4,2,0,3><<<g32,cb,0,stream>>>(Dd, c2b_w, out1, msrc+96, md+96, mscale+96, nullptr, A, nullptr);
  conv3x3<32,32,4,3,0,3><<<g32,cb,0,stream>>>(Dd, c2b_w, out1, msrc+96, md+96, mscale+96, nullptr, A, nullptr);
}

// Round 5
// 3660.559 us; speedup vs baseline: 1.3666x; 1.2887x over previous
//
#include <hip/hip_runtime.h>
#include <math.h>

#define HW 320
#define IMGSZ (HW*HW)
#define NB 4

__device__ __forceinline__ float4 ld4(const float* p){ return *reinterpret_cast<const float4*>(p); }

// ---------------------------------------------------------------------------
// adconv metadata: indexs=argmax(para,1); perm=stable argsort(indexs);
// mul[t]=sum(para max | idx==t)/max(cnt,1)+1. Slot k: src=perm[k],
// d=indexs[src]+1, scale=mul[indexs[src]].
// ---------------------------------------------------------------------------
__global__ void meta_kernel(const float* p0,const float* p1,const float* p2,
                            const float* p3,const float* p4,const float* p5,
                            int* msrc,int* md,float* mscale){
  if (threadIdx.x != 0) return;
  int set = blockIdx.x;
  const float* ps[6] = {p0,p1,p2,p3,p4,p5};
  const int Ts[6] = {1,3,1,3,1,3};   // c1f, c2f, c1b, c2b, c1g, c2g
  const float* para = ps[set];
  int T = Ts[set];
  int idx[32]; float mx[32];
  for (int c=0;c<32;c++){
    int best=0; float bv=para[c*T];
    for (int t=1;t<T;t++){ float v=para[c*T+t]; if (v>bv){bv=v;best=t;} }
    idx[c]=best; mx[c]=bv;
  }
  float sum[3]={0.f,0.f,0.f}; int cnt[3]={0,0,0};
  for (int c=0;c<32;c++){ sum[idx[c]] += mx[c]; cnt[idx[c]]++; }
  float mul[3];
  for (int t=0;t<3;t++) mul[t] = sum[t]/fmaxf((float)cnt[t],1.f)+1.f;
  int off[3]; off[0]=0; off[1]=cnt[0]; off[2]=cnt[0]+cnt[1];
  int perm[32];
  for (int c=0;c<32;c++) perm[off[idx[c]]++] = c;   // stable counting sort
  for (int k=0;k<32;k++){
    int s = perm[k];
    msrc[set*32+k]=s; md[set*32+k]=idx[s]+1; mscale[set*32+k]=mul[idx[s]];
  }
}

// u = x + xi*(x - xprev)
__global__ void ew_u(const float* __restrict__ x, const float* __restrict__ xprev,
                     const float* __restrict__ t_p, float* __restrict__ u, int n4){
  int i = blockIdx.x*blockDim.x + threadIdx.x;
  if (i >= n4) return;
  float t = *t_p;
  float tplus = (1.f + sqrtf(1.f + 4.f*t*t)) * 0.5f;
  float xi = (t - 1.f)/tplus;
  float4 xv = ld4(x + 4*i); float4 pv = ld4(xprev + 4*i);
  float4 r;
  r.x = xv.x + xi*(xv.x-pv.x);
  r.y = xv.y + xi*(xv.y-pv.y);
  r.z = xv.z + xi*(xv.z-pv.z);
  r.w = xv.w + xi*(xv.w-pv.w);
  *reinterpret_cast<float4*>(u + 4*i) = r;
}

// phi[b,c,blk,m] (per-channel!)   grid(100,3,4) x 256
__global__ void phi_fwd(const float* __restrict__ u, const float* __restrict__ PhiW,
                        float* __restrict__ phi){
  int blk = blockIdx.x, c = blockIdx.y, b = blockIdx.z;
  int bh = blk/10, bw = blk%10;
  __shared__ float ub[1024];
  int tid = threadIdx.x;
  {
    int i = tid >> 3, j4 = (tid & 7) << 2;
    const float* src = u + (size_t)((b*3 + c)*HW + bh*32 + i)*HW + bw*32 + j4;
    *reinterpret_cast<float4*>(ub + i*32 + j4) = ld4(src);
  }
  __syncthreads();
  int m = tid;
  const float* wp = PhiW + (size_t)(m*3 + c)*1024;
  float acc = 0.f;
  #pragma unroll 8
  for (int q = 0; q < 1024; q += 4){
    float4 w = ld4(wp + q);
    float4 uv = *reinterpret_cast<const float4*>(ub + q);
    acc += w.x*uv.x + w.y*uv.y + w.z*uv.z + w.w*uv.w;
  }
  phi[((size_t)(b*3 + c)*100 + blk)*256 + m] = acc;
}

// x_input = u - lam*phitphi + lam*PhiTb   grid(100,3,4) x 256
__global__ void phit_zeta(const float* __restrict__ phi, const float* __restrict__ PhiTW,
                          const float* __restrict__ u, const float* __restrict__ PhiTb,
                          const float* __restrict__ lam_p, float* __restrict__ x_input){
  int blk = blockIdx.x, c = blockIdx.y, b = blockIdx.z;
  int bh = blk/10, bw = blk%10;
  __shared__ float pb[256];
  int tid = threadIdx.x;
  pb[tid] = phi[((size_t)(b*3 + c)*100 + blk)*256 + tid];
  __syncthreads();
  float lam = *lam_p;
  for (int nn = tid; nn < 1024; nn += 256){
    const float* wp = PhiTW + (size_t)(c*1024 + nn)*256;
    float acc = 0.f;
    #pragma unroll 8
    for (int q=0;q<256;q+=4){
      float4 w = ld4(wp+q);
      float4 pv = *reinterpret_cast<const float4*>(pb+q);
      acc += w.x*pv.x + w.y*pv.y + w.z*pv.z + w.w*pv.w;
    }
    int i = nn>>5, j = nn&31;
    size_t g = (size_t)((b*3+c)*HW + bh*32+i)*HW + bw*32 + j;
    x_input[g] = u[g] - lam*acc + lam*PhiTb[g];
  }
}

// ---------------------------------------------------------------------------
// 3x3 conv, "same", dilation D (template). Block (16,16) = 64x32 px tile,
// thread tile 4x2 px, NK output-channel slots.
// Register budget (the round-3/4 lesson): acc = NK*8 = 32 regs (4x4 tile's 64
// made the allocator spill at VGPR_Count=76, VALUBusy 10%). Total working set
// ~90 regs -> fits the (256,4)=128-VGPR budget, no spills, 2x the blocks.
// Branch-free FMA core: inactive slots get zeroed weights in LDS.
// ITRANS: 0 none,1 relu,2 soft-thr. EPI: 0 none,1 relu,2 merge,3 sub.
// Grid (COUT/NK, 50, NB), kgroup fastest-varying for L2 tile reuse.
// ---------------------------------------------------------------------------
template<int CIN, int COUT, int NK, int D, int ITRANS, int EPI>
__global__ __launch_bounds__(256, 4)
void conv3x3(const float* __restrict__ in, const float* __restrict__ wts,
             float* __restrict__ out,
             const int* __restrict__ msrc, const int* __restrict__ md,
             const float* __restrict__ mscale,
             const float* __restrict__ thr_p,
             const float* __restrict__ epi_ptr,
             const float* __restrict__ ms_p){
  const int kg = blockIdx.x;
  const int b  = blockIdx.z;
  const int k0 = kg*NK;
  const int tile = blockIdx.y;     // 50 tiles: 5 in x, 10 in y

  bool act[NK]; float scl[NK]; bool any = false;
  #pragma unroll
  for (int kk=0;kk<NK;kk++){
    int k = k0+kk;
    int d = md ? md[k] : 1;
    act[kk] = (d==D);
    scl[kk] = mscale ? mscale[k] : 1.f;
    any = any || act[kk];
  }
  if (!any) return;   // wave-uniform

  __shared__ float wsm[NK*CIN*12];   // 9 taps padded to 12 for float4 reads
  int tid = threadIdx.y*16 + threadIdx.x;
  for (int q = tid; q < NK*CIN*9; q += 256){
    int kk = q/(CIN*9); int rem = q - kk*(CIN*9); int ic = rem/9; int t = rem - ic*9;
    int src = msrc ? msrc[k0+kk] : (k0+kk);
    wsm[(kk*CIN+ic)*12 + t] = act[kk] ? wts[(size_t)src*(CIN*9) + rem] : 0.f;
  }
  __syncthreads();

  const int x0 = (tile%5)*64 + threadIdx.x*4;
  const int y0 = (tile/5)*32 + threadIdx.y*2;
  const float thr = (ITRANS==2) ? *thr_p : 0.f;
  float acc[NK][2][4] = {};

  for (int ic=0; ic<CIN; ++ic){
    const float* ip = in + (size_t)(b*CIN+ic)*IMGSZ;
    float wk[NK][9];
    #pragma unroll
    for (int kk=0;kk<NK;kk++){
      const float* wp = &wsm[(kk*CIN+ic)*12];
      float4 a = *reinterpret_cast<const float4*>(wp);
      float4 bb= *reinterpret_cast<const float4*>(wp+4);
      float4 cc= *reinterpret_cast<const float4*>(wp+8);
      wk[kk][0]=a.x; wk[kk][1]=a.y; wk[kk][2]=a.z; wk[kk][3]=a.w;
      wk[kk][4]=bb.x; wk[kk][5]=bb.y; wk[kk][6]=bb.z; wk[kk][7]=bb.w;
      wk[kk][8]=cc.x;
    }
    #pragma unroll
    for (int r=0; r<2+2*D; ++r){
      int yr = y0 - D + r;
      if (yr < 0 || yr >= HW) continue;
      const float* rp = ip + (size_t)yr*HW;
      float4 v0 = (x0 >= 4)    ? ld4(rp + x0-4) : float4{0.f,0.f,0.f,0.f};
      float4 v1 = ld4(rp + x0);
      float4 v2 = (x0+4 < HW)  ? ld4(rp + x0+4) : float4{0.f,0.f,0.f,0.f};
      float w12[12] = {v0.x,v0.y,v0.z,v0.w, v1.x,v1.y,v1.z,v1.w, v2.x,v2.y,v2.z,v2.w};
      if (ITRANS==1){
        #pragma unroll
        for (int q=0;q<12;q++) w12[q] = fmaxf(w12[q],0.f);
      } else if (ITRANS==2){
        #pragma unroll
        for (int q=0;q<12;q++){
          float a = fabsf(w12[q]) - thr;
          w12[q] = (a > 0.f) ? copysignf(a, w12[q]) : 0.f;
        }
      }
      #pragma unroll
      for (int kk=0;kk<NK;kk++){
        #pragma unroll
        for (int ky=0; ky<3; ++ky){
          int j = r - ky*D;
          if (j >= 0 && j < 2){
            #pragma unroll
            for (int p=0;p<4;p++){
              #pragma unroll
              for (int kx=0;kx<3;kx++)
                acc[kk][j][p] += wk[kk][ky*3+kx] * w12[4 + p + (kx-1)*D];
            }
          }
        }
      }
    }
  }

  float ms = (EPI==2) ? *ms_p : 0.f;
  #pragma unroll
  for (int kk=0;kk<NK;kk++){
    if (!act[kk]) continue;   // store only live slots
    int k = k0+kk;
    #pragma unroll
    for (int j=0;j<2;j++){
      size_t oidx = ((size_t)(b*COUT + k)*HW + (y0+j))*HW + x0;
      float4 o;
      float* op = reinterpret_cast<float*>(&o);
      float4 e;
      if (EPI==2 || EPI==3) e = ld4(epi_ptr + oidx);
      #pragma unroll
      for (int p=0;p<4;p++){
        float v = acc[kk][j][p]*scl[kk];
        if (EPI==1) v = fmaxf(v,0.f);
        else if (EPI==2) v = reinterpret_cast<float*>(&e)[p] + ms*v;
        else if (EPI==3) v = v - reinterpret_cast<float*>(&e)[p];
        op[p] = v;
      }
      *reinterpret_cast<float4*>(out + oidx) = o;
    }
  }
}

// ---------------------------------------------------------------------------
extern "C" void kernel_launch(void* const* d_in, const int* in_sizes, int n_in,
                              void* d_out, int out_size, void* d_ws, size_t ws_size,
                              hipStream_t stream) {
  const float* xprev = (const float*)d_in[0];
  const float* x     = (const float*)d_in[1];
  const float* PhiW  = (const float*)d_in[2];
  const float* PhiTW = (const float*)d_in[3];
  const float* PhiTb = (const float*)d_in[4];
  const float* lam   = (const float*)d_in[5];
  const float* sthr  = (const float*)d_in[6];
  const float* t_p   = (const float*)d_in[7];
  const float* mrg   = (const float*)d_in[8];
  const float* convD = (const float*)d_in[9];
  const float* conv3G= (const float*)d_in[10];
  const float* c1f_w=(const float*)d_in[11]; const float* c1f_p=(const float*)d_in[12];
  const float* c2f_w=(const float*)d_in[13]; const float* c2f_p=(const float*)d_in[14];
  const float* c1b_w=(const float*)d_in[15]; const float* c1b_p=(const float*)d_in[16];
  const float* c2b_w=(const float*)d_in[17]; const float* c2b_p=(const float*)d_in[18];
  const float* c1g_w=(const float*)d_in[19]; const float* c1g_p=(const float*)d_in[20];
  const float* c2g_w=(const float*)d_in[21]; const float* c2g_p=(const float*)d_in[22];

  char* ws = (char*)d_ws;
  const size_t BIG = (size_t)NB*32*IMGSZ*sizeof(float);     // 52,428,800
  float* A       = (float*)(ws);                // x_D (kept for symloss)
  float* Bb      = (float*)(ws + BIG);
  float* Cc      = (float*)(ws + 2*BIG);        // x_forward (kept)
  float* Dd      = (float*)(ws + 3*BIG);
  float* x_input = (float*)(ws + 4*BIG);                      // 4.9 MB
  float* u       = (float*)(ws + 4*BIG + 4915200);            // 4.9 MB
  float* phi     = (float*)(ws + 4*BIG + 2*4915200);          // 4.9 MB (per-channel)
  char*  mbase   = ws + 4*BIG + 3*4915200;
  int*   msrc    = (int*)(mbase);
  int*   md      = (int*)(mbase + 6*32*4);
  float* mscale  = (float*)(mbase + 2*6*32*4);

  float* out0 = (float*)d_out;
  float* out1 = out0 + (size_t)NB*3*IMGSZ;

  dim3 cb(16,16);
  dim3 g32(8,50,NB);    // 32 out channels / NK=4, 50 tiles of 64x32
  dim3 g3(3,50,NB);     // 3 out channels, NK=1

  // meta sets: 0=c1f 1=c2f 2=c1b 3=c2b 4=c1g 5=c2g
  meta_kernel<<<6, 64, 0, stream>>>(c1f_p,c2f_p,c1b_p,c2b_p,c1g_p,c2g_p, msrc,md,mscale);

  ew_u<<<1200, 256, 0, stream>>>(x, xprev, t_p, u, 307200);
  phi_fwd<<<dim3(100,3,NB), 256, 0, stream>>>(u, PhiW, phi);
  phit_zeta<<<dim3(100,3,NB), 256, 0, stream>>>(phi, PhiTW, u, PhiTb, lam, x_input);

  // x_D = conv_D(x_input)
  conv3x3<3,32,4,1,0,0><<<g32,cb,0,stream>>>(x_input, convD, A, nullptr,nullptr,nullptr, nullptr,nullptr,nullptr);
  // h1 = relu(adconv(x_D, c1f))
  conv3x3<32,32,4,1,0,1><<<g32,cb,0,stream>>>(A, c1f_w, Bb, msrc, md, mscale, nullptr,nullptr,nullptr);
  // x_forward = adconv(h1, c2f)
  conv3x3<32,32,4,1,0,0><<<g32,cb,0,stream>>>(Bb, c2f_w, Cc, msrc+32, md+32, mscale+32, nullptr,nullptr,nullptr);
  conv3x3<32,32,4,2,0,0><<<g32,cb,0,stream>>>(Bb, c2f_w, Cc, msrc+32, md+32, mscale+32, nullptr,nullptr,nullptr);
  conv3x3<32,32,4,3,0,0><<<g32,cb,0,stream>>>(Bb, c2f_w, Cc, msrc+32, md+32, mscale+32, nullptr,nullptr,nullptr);
  // h2 = relu(adconv(soft(x_forward), c1f))
  conv3x3<32,32,4,1,2,1><<<g32,cb,0,stream>>>(Cc, c1f_w, Dd, msrc, md, mscale, sthr,nullptr,nullptr);
  // x_backward = adconv(h2, c2b)
  conv3x3<32,32,4,1,0,0><<<g32,cb,0,stream>>>(Dd, c2b_w, Bb, msrc+96, md+96, mscale+96, nullptr,nullptr,nullptr);
  conv3x3<32,32,4,2,0,0><<<g32,cb,0,stream>>>(Dd, c2b_w, Bb, msrc+96, md+96, mscale+96, nullptr,nullptr,nullptr);
  conv3x3<32,32,4,3,0,0><<<g32,cb,0,stream>>>(Dd, c2b_w, Bb, msrc+96, md+96, mscale+96, nullptr,nullptr,nullptr);
  // h3 = adconv(relu(x_backward), c1g)
  conv3x3<32,32,4,1,1,0><<<g32,cb,0,stream>>>(Bb, c1g_w, Dd, msrc+128, md+128, mscale+128, nullptr,nullptr,nullptr);
  // h4 = adconv(relu(h3), c2g)
  conv3x3<32,32,4,1,1,0><<<g32,cb,0,stream>>>(Dd, c2g_w, Bb, msrc+160, md+160, mscale+160, nullptr,nullptr,nullptr);
  conv3x3<32,32,4,2,1,0><<<g32,cb,0,stream>>>(Dd, c2g_w, Bb, msrc+160, md+160, mscale+160, nullptr,nullptr,nullptr);
  conv3x3<32,32,4,3,1,0><<<g32,cb,0,stream>>>(Dd, c2g_w, Bb, msrc+160, md+160, mscale+160, nullptr,nullptr,nullptr);
  // x_pred = x_input + mergeScale * conv3_G(h4)  -> out0
  conv3x3<32,3,1,1,0,2><<<g3,cb,0,stream>>>(Bb, conv3G, out0, nullptr,nullptr,nullptr, nullptr, x_input, mrg);
  // h5 = relu(adconv(x_forward, c1b))
  conv3x3<32,32,4,1,0,1><<<g32,cb,0,stream>>>(Cc, c1b_w, Dd, msrc+64, md+64, mscale+64, nullptr,nullptr,nullptr);
  // symloss = adconv(h5, c2b) - x_D  -> out1
  conv3x3<32,32,4,1,0,3><<<g32,cb,0,stream>>>(Dd, c2b_w, out1, msrc+96, md+96, mscale+96, nullptr, A, nullptr);
  conv3x3<32,32,4,2,0,3><<<g32,cb,0,stream>>>(Dd, c2b_w, out1, msrc+96, md+96, mscale+96, nullptr, A, nullptr);
  conv3x3<32,32,4,3,0,3><<<g32,cb,0,stream>>>(Dd, c2b_w, out1, msrc+96, md+96, mscale+96, nullptr, A, nullptr);
}